// Round 7
// baseline (1202.740 us; speedup 1.0000x reference)
//
#include <hip/hip_runtime.h>
#include <hip/hip_bf16.h>

typedef __hip_bfloat16 bf16;
typedef __attribute__((ext_vector_type(8))) short short8;
typedef __attribute__((ext_vector_type(4))) short short4_t;
typedef __attribute__((ext_vector_type(4))) float float4_t;
typedef __attribute__((ext_vector_type(2))) float float2v;
typedef __attribute__((ext_vector_type(2))) unsigned int uint2v;

__device__ __forceinline__ short f2bs(float f) {
    bf16 b = __float2bfloat16(f);
    return *(short*)&b;
}

// DPP-based 16-lane all-reduce sum: 4 full-rate VALU steps, no LDS traffic.
template <int CTRL>
__device__ __forceinline__ float dpp_addf(float x) {
    int s = __builtin_amdgcn_update_dpp(
        0, __builtin_bit_cast(int, x), CTRL, 0xf, 0xf, true);
    return x + __builtin_bit_cast(float, s);
}
__device__ __forceinline__ float rowsum16(float x) {
    x = dpp_addf<0xB1>(x);    // quad_perm [1,0,3,2]
    x = dpp_addf<0x4E>(x);    // quad_perm [2,3,0,1]
    x = dpp_addf<0x141>(x);   // row_half_mirror
    x = dpp_addf<0x140>(x);   // row_mirror
    return x;
}

// ---------------------------------------------------------------- CSR build
// Bucketed CSR: lists indexed by (dst, src>>10). Each bucket = 1024 src rows
// = 4MB of cat rows (one XCD L2). All waves sweep buckets in the same order ->
// the live gather window stays L2-sized instead of 82MB. Edge order within a
// dst is bucket-ascending; gat reads the concatenation (pure summation reorder).
__global__ __launch_bounds__(256) void count_kernel(const int* __restrict__ ei,
                                                    int* __restrict__ cnt,
                                                    int E, int N, int NB) {
    int e = blockIdx.x * 256 + threadIdx.x;
    if (e >= E + N) return;
    int s, d;
    if (e < E) { s = ei[e]; d = ei[(size_t)E + e]; }
    else       { s = e - E; d = e - E; }               // self-loop
    atomicAdd(&cnt[(size_t)d * NB + (s >> 10)], 1);
}

__global__ __launch_bounds__(1024) void scan_kernel(const int* __restrict__ cnt,
                                                    int* __restrict__ rowptr, int M) {
    __shared__ int ps[1024];
    const int tid = threadIdx.x;
    const int chunk = (M + 1023) / 1024;
    const int base = tid * chunk;
    int s = 0;
    for (int i = 0; i < chunk; ++i) { int j = base + i; if (j < M) s += cnt[j]; }
    ps[tid] = s;
    __syncthreads();
    for (int off = 1; off < 1024; off <<= 1) {
        int v = (tid >= off) ? ps[tid - off] : 0;
        __syncthreads();
        ps[tid] += v;
        __syncthreads();
    }
    int run = (tid == 0) ? 0 : ps[tid - 1];
    for (int i = 0; i < chunk; ++i) {
        int j = base + i;
        if (j < M) { rowptr[j] = run; run += cnt[j]; }
    }
    if (tid == 1023) rowptr[M] = run;
}

// stores BYTE offsets (src * 4096): both gat layers use row stride 2048 bf16
__global__ __launch_bounds__(256) void scatter_kernel(const int* __restrict__ ei,
                                                      const int* __restrict__ rowptr,
                                                      int* __restrict__ cursor,
                                                      int* __restrict__ csr_off,
                                                      int E, int N, int NB) {
    int e = blockIdx.x * 256 + threadIdx.x;
    if (e >= E + N) return;
    int s, d;
    if (e < E) { s = ei[e]; d = ei[(size_t)E + e]; }
    else       { s = e - E; d = e - E; }
    size_t b = (size_t)d * NB + (s >> 10);
    int pos = atomicAdd(&cursor[b], 1);
    csr_off[rowptr[b] + pos] = s * 4096;
}

// ---------------------------------------------------------------- weight prep
// z=0..6: LDS-tiled transpose+cast; z=7: bias concat (fused, saves a dispatch)
__global__ __launch_bounds__(256) void transpose_w_kernel(
        const float* __restrict__ W_in,
        const float* __restrict__ c1_Wl, const float* __restrict__ c1_Wr,
        const float* __restrict__ a_Wl, const float* __restrict__ a_Wr,
        const float* __restrict__ k_Wl, const float* __restrict__ k_Wr,
        bf16* __restrict__ Wt,
        const float* __restrict__ c1_bl, const float* __restrict__ c1_br,
        const float* __restrict__ a_bl, const float* __restrict__ a_br,
        const float* __restrict__ k_bl, const float* __restrict__ k_br,
        float* __restrict__ b1, float* __restrict__ bak) {
    if (blockIdx.z == 7) {                       // bias slice
        int flat = blockIdx.y * 16 + blockIdx.x;
        if (flat >= 12) return;
        int i = flat * 256 + threadIdx.x;
        if (i < 1024) {
            b1[i] = (i < 512) ? c1_bl[i] : c1_br[i - 512];
        } else if (i < 3072) {
            int j = i - 1024;                    // [a_bl | a_br | k_bl | k_br]
            const float* b = (j < 512) ? a_bl : (j < 1024) ? a_br
                           : (j < 1536) ? k_bl : k_br;
            bak[j] = b[j & 511];
        }
        return;
    }
    __shared__ float tile[32][33];
    const float* src; int nc, drow;
    switch (blockIdx.z) {
        case 0: src = W_in;  nc = 128; drow = 0;    break;
        case 1: src = c1_Wl; nc = 512; drow = 128;  break;
        case 2: src = c1_Wr; nc = 512; drow = 640;  break;
        case 3: src = a_Wl;  nc = 512; drow = 1152; break;
        case 4: src = a_Wr;  nc = 512; drow = 1664; break;
        case 5: src = k_Wl;  nc = 512; drow = 2176; break;
        default: src = k_Wr; nc = 512; drow = 2688; break;
    }
    const int n0 = blockIdx.x * 32;
    if (n0 >= nc) return;
    const int k0 = blockIdx.y * 32;
    const int tx = threadIdx.x & 31, ty = threadIdx.x >> 5;
#pragma unroll
    for (int i = 0; i < 4; ++i)
        tile[ty + i * 8][tx] = src[(size_t)(k0 + ty + i * 8) * nc + n0 + tx];
    __syncthreads();
#pragma unroll
    for (int i = 0; i < 4; ++i)
        Wt[(size_t)(drow + n0 + ty + i * 8) * 128 + k0 + tx] =
            __float2bfloat16(tile[tx][ty + i * 8]);
}

// ---------------------------------------------------------------- MFMA GEMM
__global__ __launch_bounds__(256, 2) void gemm_mfma_kernel(
        const float* __restrict__ A, const bf16* __restrict__ Ab,
        const bf16* __restrict__ Wt,
        const float* __restrict__ bias,
        float* __restrict__ outF, bf16* __restrict__ outB,
        int M, int ldc, int relu) {
    __shared__ short As[128][136];   // [m][k]
    __shared__ short Bs[128][136];   // [n][k]
    const int tid = threadIdx.x;
    const int m0 = blockIdx.x * 128;
    const int n0 = blockIdx.y * 128;

    if (Ab) {
        short8 zero8;
#pragma unroll
        for (int q = 0; q < 8; ++q) zero8[q] = 0;
#pragma unroll
        for (int i = 0; i < 8; ++i) {            // stage A (bf16 direct)
            int idx = i * 256 + tid;
            int r = idx >> 4, k8 = (idx & 15) * 8;
            int gm = m0 + r;
            short8 s = (gm < M) ? *(const short8*)&Ab[(size_t)gm * 128 + k8] : zero8;
            *(short8*)&As[r][k8] = s;
        }
    } else {
#pragma unroll
        for (int i = 0; i < 16; ++i) {           // stage A (fp32 -> bf16)
            int idx = i * 256 + tid;
            int r = idx >> 5, k4 = (idx & 31) * 4;
            int gm = m0 + r;
            float4 v = (gm < M) ? *(const float4*)&A[(size_t)gm * 128 + k4]
                                : make_float4(0.f, 0.f, 0.f, 0.f);
            short4_t s;
            s.x = f2bs(v.x); s.y = f2bs(v.y); s.z = f2bs(v.z); s.w = f2bs(v.w);
            *(short4_t*)&As[r][k4] = s;
        }
    }
#pragma unroll
    for (int i = 0; i < 8; ++i) {                // stage B
        int idx = i * 256 + tid;
        int nr = idx >> 4, k8 = (idx & 15) * 8;
        *(short8*)&Bs[nr][k8] = *(const short8*)&Wt[(size_t)(n0 + nr) * 128 + k8];
    }
    __syncthreads();

    const int lane = tid & 63;
    const int w = tid >> 6;
    const int wm = (w >> 1) * 64, wn = (w & 1) * 64;
    const int fr = lane & 15;
    const int fq = (lane >> 4) * 8;

    float4_t acc[4][4] = {};
#pragma unroll
    for (int kk = 0; kk < 128; kk += 32) {
        short8 a[4], b[4];
#pragma unroll
        for (int t = 0; t < 4; ++t) a[t] = *(const short8*)&As[wm + t * 16 + fr][kk + fq];
#pragma unroll
        for (int t = 0; t < 4; ++t) b[t] = *(const short8*)&Bs[wn + t * 16 + fr][kk + fq];
#pragma unroll
        for (int ti = 0; ti < 4; ++ti)
#pragma unroll
            for (int tj = 0; tj < 4; ++tj)
                acc[ti][tj] = __builtin_amdgcn_mfma_f32_16x16x32_bf16(
                    a[ti], b[tj], acc[ti][tj], 0, 0, 0);
    }

    const int r0 = (lane >> 4) * 4;              // C/D: col=lane&15, row=quad*4+reg
#pragma unroll
    for (int ti = 0; ti < 4; ++ti) {
#pragma unroll
        for (int tj = 0; tj < 4; ++tj) {
            int col = n0 + wn + tj * 16 + fr;
            float bz = bias[col];
#pragma unroll
            for (int r = 0; r < 4; ++r) {
                size_t row = m0 + wm + ti * 16 + r0 + r;
                float v = acc[ti][tj][r] + bz;
                if (relu) v = fmaxf(v, 0.f);
                if (outF) outF[row * ldc + col] = v;
                if (outB) outB[row * ldc + col] = __float2bfloat16(v);
            }
        }
    }
}

// ---------------------------------------------------------------- GAT layer 1
// ONE WAVE PER NODE (4 nodes/block, no barriers, no LDS). 4 heads x 16 lanes,
// 8 ch/lane. e wave-uniform -> scalar loop guards. Depth-2 row prefetch.
__global__ __launch_bounds__(256) void gat_kernel(
        const bf16* __restrict__ xl, const bf16* __restrict__ xr,  // stride 2048
        const float* __restrict__ att,      // [4*128]
        const int* __restrict__ rowptr, const int* __restrict__ csr_off,
        const float* __restrict__ h_res,    // [N,128]
        const float* __restrict__ gbias,    // [128]
        const float* __restrict__ ln_g, const float* __restrict__ ln_b,
        float* __restrict__ h_out, bf16* __restrict__ h_outb, int N, int NB) {
    const int n = blockIdx.x * 4 + (threadIdx.x >> 6);
    if (n >= N) return;
    const int lane = threadIdx.x & 63;
    const int sl = lane & 15;
    const int hc = (lane >> 4) * 128 + sl * 8;   // channel in [0,512)

    float2v a2[4], xr2[4];
    {
        const float* ap = att + hc;
        short8 v = *(const short8*)(xr + (size_t)n * 2048 + hc);
        const unsigned int* uv = (const unsigned int*)&v;
#pragma unroll
        for (int j = 0; j < 4; ++j) {
            a2[j].x = ap[2 * j]; a2[j].y = ap[2 * j + 1];
            unsigned u = uv[j];
            xr2[j].x = __uint_as_float(u << 16);
            xr2[j].y = __uint_as_float(u & 0xffff0000u);
        }
    }
    const int rs = rowptr[(size_t)n * NB];
    const int re = rowptr[(size_t)n * NB + NB];
    const char* xlh = (const char*)xl + (size_t)hc * 2;

    float l = 0.f;
    float2v acc2[4] = {};
    int o0 = csr_off[rs];
    short8 va = *(const short8*)(xlh + o0);
    int o1 = (rs + 1 < re) ? csr_off[rs + 1] : o0;
    short8 vb = *(const short8*)(xlh + o1);
    int o2 = (rs + 2 < re) ? csr_off[rs + 2] : o0;

    for (int e = rs; e < re; ++e) {
        short8 cur = va; va = vb;
        if (e + 2 < re) {                        // wave-uniform -> scalar branch
            vb = *(const short8*)(xlh + o2);
            o2 = (e + 3 < re) ? csr_off[e + 3] : o0;
        }
        const unsigned int* uv = (const unsigned int*)&cur;
        float2v pa = {0.f, 0.f}, pb = {0.f, 0.f};
        float2v xs[4];
#pragma unroll
        for (int j = 0; j < 4; ++j) {
            unsigned u = uv[j];
            float2v x;
            x.x = __uint_as_float(u << 16);
            x.y = __uint_as_float(u & 0xffff0000u);
            xs[j] = x;
            float2v t = x + xr2[j];
            float2v ta = __builtin_bit_cast(float2v,
                           __builtin_bit_cast(uint2v, t) & 0x7fffffffu);
            pa = __builtin_elementwise_fma(a2[j], t, pa);
            pb = __builtin_elementwise_fma(a2[j], ta, pb);
        }
        float p = rowsum16(0.6f * (pa.x + pa.y) + 0.4f * (pb.x + pb.y));
        float wv = __expf(fminf(p, 60.f));       // scores O(+-4); clamp for safety
        l += wv;
        float2v ws = {wv, wv};
#pragma unroll
        for (int j = 0; j < 4; ++j)
            acc2[j] = __builtin_elementwise_fma(ws, xs[j], acc2[j]);
    }

    float* accf = (float*)acc2;
    const float inv = 0.25f / (l + 1e-16f);
#pragma unroll
    for (int j = 0; j < 8; ++j) accf[j] *= inv;
#pragma unroll
    for (int off = 16; off <= 32; off <<= 1)
#pragma unroll
        for (int j = 0; j < 8; ++j) accf[j] += __shfl_xor(accf[j], off, 64);

    if (lane < 16) {
        const int cb = sl * 8;
        const float* hr = h_res + (size_t)n * 128 + cb;
        float vv[8];
#pragma unroll
        for (int j = 0; j < 8; ++j) vv[j] = accf[j] + gbias[cb + j] + hr[j];
        float t1 = 0.f, t2 = 0.f;
#pragma unroll
        for (int j = 0; j < 8; ++j) { t1 += vv[j]; t2 += vv[j] * vv[j]; }
        const float s1 = rowsum16(t1), s2 = rowsum16(t2);
        const float mu   = s1 * 0.0078125f;
        const float var  = s2 * 0.0078125f - mu * mu;
        const float rstd = rsqrtf(var + 1e-5f);
        float y[8];
#pragma unroll
        for (int j = 0; j < 8; ++j) {
            y[j] = fmaf((vv[j] - mu) * rstd, ln_g[cb + j], ln_b[cb + j]);
            y[j] = fmaxf(y[j], 0.f);
        }
        *(float4*)(h_out + (size_t)n * 128 + cb) = make_float4(y[0], y[1], y[2], y[3]);
        *(float4*)(h_out + (size_t)n * 128 + cb + 4) = make_float4(y[4], y[5], y[6], y[7]);
        short8 yb;
#pragma unroll
        for (int j = 0; j < 8; ++j) yb[j] = f2bs(y[j]);
        *(short8*)(h_outb + (size_t)n * 128 + cb) = yb;
    }
}

// ---------------------------------------------------------------- merged actor+critic GAT
// cat cols [xla|xra|xlk|xrk]: per edge read xla at +0 and xlk at +2048B of the
// same 4KB row (R4-proven split). Lanes 0-15 epilogue actor, 16-31 critic.
__global__ __launch_bounds__(256) void gat2_kernel(
        const bf16* __restrict__ cat,       // [*][2048]
        const float* __restrict__ a_att, const float* __restrict__ k_att,
        const int* __restrict__ rowptr, const int* __restrict__ csr_off,
        const float* __restrict__ h_res,    // [N,128] = h1
        const float* __restrict__ a_gb, const float* __restrict__ k_gb,
        const float* __restrict__ aln_g, const float* __restrict__ aln_b,
        const float* __restrict__ kln_g, const float* __restrict__ kln_b,
        const float* __restrict__ ah_W, const float* __restrict__ ah_b,
        const float* __restrict__ kh_W, const float* __restrict__ kh_b,
        float* __restrict__ out_logits, float* __restrict__ out_value,
        int N, int NB) {
    const int n = blockIdx.x * 4 + (threadIdx.x >> 6);
    if (n >= N) return;
    const int lane = threadIdx.x & 63;
    const int sl = lane & 15;
    const int hc = (lane >> 4) * 128 + sl * 8;

    float2v aa[4], ak[4], xra[4], xrk[4];
    {
        const float* apa = a_att + hc;
        const float* apk = k_att + hc;
        short8 vra = *(const short8*)(cat + (size_t)n * 2048 + 512 + hc);
        short8 vrk = *(const short8*)(cat + (size_t)n * 2048 + 1536 + hc);
        const unsigned int* ua = (const unsigned int*)&vra;
        const unsigned int* uk = (const unsigned int*)&vrk;
#pragma unroll
        for (int j = 0; j < 4; ++j) {
            aa[j].x = apa[2 * j]; aa[j].y = apa[2 * j + 1];
            ak[j].x = apk[2 * j]; ak[j].y = apk[2 * j + 1];
            unsigned u = ua[j];
            xra[j].x = __uint_as_float(u << 16);
            xra[j].y = __uint_as_float(u & 0xffff0000u);
            u = uk[j];
            xrk[j].x = __uint_as_float(u << 16);
            xrk[j].y = __uint_as_float(u & 0xffff0000u);
        }
    }
    const int rs = rowptr[(size_t)n * NB];
    const int re = rowptr[(size_t)n * NB + NB];
    const char* xlh = (const char*)cat + (size_t)hc * 2;   // +o: xla, +o+2048: xlk

    float la = 0.f, lk = 0.f;
    float2v acca[4] = {}, acck[4] = {};
    int o0 = csr_off[rs];
    short8 vaa = *(const short8*)(xlh + o0);
    short8 vak = *(const short8*)(xlh + o0 + 2048);
    int o1 = (rs + 1 < re) ? csr_off[rs + 1] : o0;
    short8 vba = *(const short8*)(xlh + o1);
    short8 vbk = *(const short8*)(xlh + o1 + 2048);
    int o2 = (rs + 2 < re) ? csr_off[rs + 2] : o0;

    for (int e = rs; e < re; ++e) {
        short8 ca = vaa, ck = vak;
        vaa = vba; vak = vbk;
        if (e + 2 < re) {
            vba = *(const short8*)(xlh + o2);
            vbk = *(const short8*)(xlh + o2 + 2048);
            o2 = (e + 3 < re) ? csr_off[e + 3] : o0;
        }
        const unsigned int* ua = (const unsigned int*)&ca;
        const unsigned int* uk = (const unsigned int*)&ck;
        float2v paa = {0.f, 0.f}, pba = {0.f, 0.f};
        float2v pak = {0.f, 0.f}, pbk = {0.f, 0.f};
        float2v xsa[4], xsk[4];
#pragma unroll
        for (int j = 0; j < 4; ++j) {
            unsigned u = ua[j];
            float2v x;
            x.x = __uint_as_float(u << 16);
            x.y = __uint_as_float(u & 0xffff0000u);
            xsa[j] = x;
            float2v t = x + xra[j];
            float2v ta = __builtin_bit_cast(float2v,
                           __builtin_bit_cast(uint2v, t) & 0x7fffffffu);
            paa = __builtin_elementwise_fma(aa[j], t, paa);
            pba = __builtin_elementwise_fma(aa[j], ta, pba);

            u = uk[j];
            x.x = __uint_as_float(u << 16);
            x.y = __uint_as_float(u & 0xffff0000u);
            xsk[j] = x;
            t = x + xrk[j];
            ta = __builtin_bit_cast(float2v,
                   __builtin_bit_cast(uint2v, t) & 0x7fffffffu);
            pak = __builtin_elementwise_fma(ak[j], t, pak);
            pbk = __builtin_elementwise_fma(ak[j], ta, pbk);
        }
        float p_a = rowsum16(0.6f * (paa.x + paa.y) + 0.4f * (pba.x + pba.y));
        float p_k = rowsum16(0.6f * (pak.x + pak.y) + 0.4f * (pbk.x + pbk.y));
        float wa = __expf(fminf(p_a, 60.f));
        float wk = __expf(fminf(p_k, 60.f));
        la += wa; lk += wk;
        float2v wsa = {wa, wa}, wsk = {wk, wk};
#pragma unroll
        for (int j = 0; j < 4; ++j) {
            acca[j] = __builtin_elementwise_fma(wsa, xsa[j], acca[j]);
            acck[j] = __builtin_elementwise_fma(wsk, xsk[j], acck[j]);
        }
    }

    float* afa = (float*)acca;
    float* afk = (float*)acck;
    const float inva = 0.25f / (la + 1e-16f);
    const float invk = 0.25f / (lk + 1e-16f);
#pragma unroll
    for (int j = 0; j < 8; ++j) { afa[j] *= inva; afk[j] *= invk; }
#pragma unroll
    for (int off = 16; off <= 32; off <<= 1)
#pragma unroll
        for (int j = 0; j < 8; ++j) {
            afa[j] += __shfl_xor(afa[j], off, 64);
            afk[j] += __shfl_xor(afk[j], off, 64);
        }

    if (lane < 32) {
        const int cb = sl * 8;
        const float* hr = h_res + (size_t)n * 128 + cb;
        float hrv[8];
#pragma unroll
        for (int j = 0; j < 8; ++j) hrv[j] = hr[j];
        if (lane < 16) {                         // actor
            float vv[8];
#pragma unroll
            for (int j = 0; j < 8; ++j) vv[j] = afa[j] + a_gb[cb + j] + hrv[j];
            float t1 = 0.f, t2 = 0.f;
#pragma unroll
            for (int j = 0; j < 8; ++j) { t1 += vv[j]; t2 += vv[j] * vv[j]; }
            const float s1 = rowsum16(t1), s2 = rowsum16(t2);
            const float mu   = s1 * 0.0078125f;
            const float var  = s2 * 0.0078125f - mu * mu;
            const float rstd = rsqrtf(var + 1e-5f);
            float d = 0.f;
#pragma unroll
            for (int j = 0; j < 8; ++j) {
                float y = fmaf((vv[j] - mu) * rstd, aln_g[cb + j], aln_b[cb + j]);
                d += fmaxf(y, 0.f) * ah_W[cb + j];
            }
            d = rowsum16(d);
            if (sl == 0) out_logits[n] = d + ah_b[0];
        } else {                                 // critic
            float vv[8];
#pragma unroll
            for (int j = 0; j < 8; ++j) vv[j] = afk[j] + k_gb[cb + j] + hrv[j];
            float t1 = 0.f, t2 = 0.f;
#pragma unroll
            for (int j = 0; j < 8; ++j) { t1 += vv[j]; t2 += vv[j] * vv[j]; }
            const float s1 = rowsum16(t1), s2 = rowsum16(t2);
            const float mu   = s1 * 0.0078125f;
            const float var  = s2 * 0.0078125f - mu * mu;
            const float rstd = rsqrtf(var + 1e-5f);
            float d = 0.f;
#pragma unroll
            for (int j = 0; j < 8; ++j) {
                float y = fmaf((vv[j] - mu) * rstd, kln_g[cb + j], kln_b[cb + j]);
                d += fmaxf(y, 0.f) * kh_W[cb + j];
            }
            d = rowsum16(d);
            if (sl == 0) out_value[n] = d + kh_b[0];
        }
    }
}

// ---------------------------------------------------------------- launch
extern "C" void kernel_launch(void* const* d_in, const int* in_sizes, int n_in,
                              void* d_out, int out_size, void* d_ws, size_t ws_size,
                              hipStream_t stream) {
    const float* x      = (const float*)d_in[0];
    const int*   ei     = (const int*)  d_in[1];
    const float* W_in   = (const float*)d_in[2];
    const float* b_in   = (const float*)d_in[3];
    const float* c1_Wl  = (const float*)d_in[4];
    const float* c1_bl  = (const float*)d_in[5];
    const float* c1_Wr  = (const float*)d_in[6];
    const float* c1_br  = (const float*)d_in[7];
    const float* c1_att = (const float*)d_in[8];
    const float* c1_b   = (const float*)d_in[9];
    const float* ln1_g  = (const float*)d_in[10];
    const float* ln1_b  = (const float*)d_in[11];
    const float* a_Wl   = (const float*)d_in[12];
    const float* a_bl   = (const float*)d_in[13];
    const float* a_Wr   = (const float*)d_in[14];
    const float* a_br   = (const float*)d_in[15];
    const float* a_att  = (const float*)d_in[16];
    const float* a_b    = (const float*)d_in[17];
    const float* aln_g  = (const float*)d_in[18];
    const float* aln_b  = (const float*)d_in[19];
    const float* ah_W   = (const float*)d_in[20];
    const float* ah_b   = (const float*)d_in[21];
    const float* k_Wl   = (const float*)d_in[22];
    const float* k_bl   = (const float*)d_in[23];
    const float* k_Wr   = (const float*)d_in[24];
    const float* k_br   = (const float*)d_in[25];
    const float* k_att  = (const float*)d_in[26];
    const float* k_b    = (const float*)d_in[27];
    const float* kln_g  = (const float*)d_in[28];
    const float* kln_b  = (const float*)d_in[29];
    const float* kh_W   = (const float*)d_in[30];
    const float* kh_b   = (const float*)d_in[31];

    const int N  = in_sizes[0] / 128;       // 20000
    const int E  = in_sizes[1] / 2;         // 320000
    const int ET = E + N;
    const int MB = (N + 127) / 128;         // 157
    const int Npad = MB * 128;              // 20096
    const int NB = (N + 1023) >> 10;        // src buckets (20): 4MB of rows each
    const int M  = N * NB;                  // bucketed CSR cells

    char* ws = (char*)d_ws;
    size_t off = 0;
    auto alloc = [&](size_t bytes) -> void* {
        void* p = ws + off;
        off += (bytes + 255) & ~(size_t)255;
        return p;
    };
    int*   rowptr  = (int*)alloc((size_t)(M + 1) * 4);
    int*   cntcur  = (int*)alloc((size_t)2 * M * 4);   // cnt | cursor
    int*   csr_off = (int*)alloc((size_t)ET * 4);
    float* h0      = (float*)alloc((size_t)Npad * 128 * 4);
    bf16*  h0b     = (bf16*)alloc((size_t)Npad * 128 * 2);
    float* h1      = (float*)alloc((size_t)Npad * 128 * 4);
    bf16*  h1b     = (bf16*)alloc((size_t)Npad * 128 * 2);
    bf16*  Wt      = (bf16*)alloc((size_t)3200 * 128 * 2);
    float* b1cat   = (float*)alloc(1024 * 4);
    float* bakcat  = (float*)alloc(2048 * 4);
    bf16*  cat     = (bf16*)alloc((size_t)Npad * 2048 * 2);  // row stride 2048 always

    int* cnt    = cntcur;
    int* cursor = cntcur + M;
    const bf16* Wt_in = Wt;
    const bf16* Wt_1  = Wt + 128 * 128;
    const bf16* Wt_ak = Wt + 128 * 128 + 1024 * 128;

    float* out_logits = (float*)d_out;
    float* out_value  = (float*)d_out + N;

    // CSR (bucketed; shared by all GAT layers) + weight prep
    hipMemsetAsync(cntcur, 0, (size_t)2 * M * 4, stream);
    count_kernel<<<(ET + 255) / 256, 256, 0, stream>>>(ei, cnt, E, N, NB);
    transpose_w_kernel<<<dim3(16, 4, 8), 256, 0, stream>>>(
        W_in, c1_Wl, c1_Wr, a_Wl, a_Wr, k_Wl, k_Wr, Wt,
        c1_bl, c1_br, a_bl, a_br, k_bl, k_br, b1cat, bakcat);
    scan_kernel<<<1, 1024, 0, stream>>>(cnt, rowptr, M);
    scatter_kernel<<<(ET + 255) / 256, 256, 0, stream>>>(ei, rowptr, cursor, csr_off,
                                                         E, N, NB);

    // h0 = relu(x @ W_in + b_in)  (fp32 for residual + bf16 for next GEMM's A)
    gemm_mfma_kernel<<<dim3(MB, 1), 256, 0, stream>>>(x, nullptr, Wt_in, b_in,
                                                      h0, h0b, N, 128, 1);
    // layer-1: [xl1|xr1] = h0 @ [Wl|Wr]  (bf16 A, cols 0..1023, row stride 2048)
    gemm_mfma_kernel<<<dim3(MB, 8), 256, 0, stream>>>(nullptr, h0b, Wt_1, b1cat,
                                                      nullptr, cat, Npad, 2048, 0);
    gat_kernel<<<(N + 3) / 4, 256, 0, stream>>>(cat, cat + 512, c1_att, rowptr, csr_off,
                                      h0, c1_b, ln1_g, ln1_b, h1, h1b, N, NB);
    // actor+critic: [xla|xra|xlk|xrk] = h1 @ [aWl|aWr|kWl|kWr]
    gemm_mfma_kernel<<<dim3(MB, 16), 256, 0, stream>>>(nullptr, h1b, Wt_ak, bakcat,
                                                       nullptr, cat, Npad, 2048, 0);
    gat2_kernel<<<(N + 3) / 4, 256, 0, stream>>>(cat, a_att, k_att, rowptr, csr_off,
                                      h1, a_b, k_b, aln_g, aln_b, kln_g, kln_b,
                                      ah_W, ah_b, kh_W, kh_b,
                                      out_logits, out_value, N, NB);
}

// Round 8
// 392.177 us; speedup vs baseline: 3.0668x; 3.0668x over previous
//
#include <hip/hip_runtime.h>
#include <hip/hip_bf16.h>

typedef __hip_bfloat16 bf16;
typedef __attribute__((ext_vector_type(8))) short short8;
typedef __attribute__((ext_vector_type(4))) short short4_t;
typedef __attribute__((ext_vector_type(4))) float float4_t;
typedef __attribute__((ext_vector_type(2))) float float2v;
typedef __attribute__((ext_vector_type(2))) unsigned int uint2v;

__device__ __forceinline__ short f2bs(float f) {
    bf16 b = __float2bfloat16(f);
    return *(short*)&b;
}

// DPP-based 16-lane all-reduce sum: 4 full-rate VALU steps, no LDS traffic.
template <int CTRL>
__device__ __forceinline__ float dpp_addf(float x) {
    int s = __builtin_amdgcn_update_dpp(
        0, __builtin_bit_cast(int, x), CTRL, 0xf, 0xf, true);
    return x + __builtin_bit_cast(float, s);
}
__device__ __forceinline__ float rowsum16(float x) {
    x = dpp_addf<0xB1>(x);    // quad_perm [1,0,3,2]
    x = dpp_addf<0x4E>(x);    // quad_perm [2,3,0,1]
    x = dpp_addf<0x141>(x);   // row_half_mirror
    x = dpp_addf<0x140>(x);   // row_mirror
    return x;
}

// ---------------------------------------------------------------- CSR build
// Bucketed CSR: lists indexed by (dst, src>>10). Each bucket = 1024 src rows
// = 4MB of cat rows (one XCD L2). All waves sweep buckets in the same order ->
// the live gather window stays L2-sized instead of 82MB. Edge order within a
// dst is bucket-ascending; gat reads the concatenation (pure summation reorder).
__global__ __launch_bounds__(256) void count_kernel(const int* __restrict__ ei,
                                                    int* __restrict__ cnt,
                                                    int E, int N, int NB) {
    int e = blockIdx.x * 256 + threadIdx.x;
    if (e >= E + N) return;
    int s, d;
    if (e < E) { s = ei[e]; d = ei[(size_t)E + e]; }
    else       { s = e - E; d = e - E; }               // self-loop
    atomicAdd(&cnt[(size_t)d * NB + (s >> 10)], 1);
}

// ---- hierarchical scan (3 passes; M up to ~1M) ----
// pass 1: per-block (1024 elems) exclusive scan -> rowptr, block total -> bsum
__global__ __launch_bounds__(256) void scan_blk_kernel(const int* __restrict__ cnt,
                                                       int* __restrict__ rowptr,
                                                       int* __restrict__ bsum, int M) {
    __shared__ int ts[256];
    const int tid = threadIdx.x;
    const int idx = blockIdx.x * 1024 + tid * 4;
    int v[4];
    int s = 0;
#pragma unroll
    for (int i = 0; i < 4; ++i) {
        int j = idx + i;
        v[i] = (j < M) ? cnt[j] : 0;
        s += v[i];
    }
    ts[tid] = s;
    __syncthreads();
    for (int off = 1; off < 256; off <<= 1) {
        int t = (tid >= off) ? ts[tid - off] : 0;
        __syncthreads();
        ts[tid] += t;
        __syncthreads();
    }
    int run = (tid == 0) ? 0 : ts[tid - 1];
    if (tid == 255) bsum[blockIdx.x] = ts[255];
#pragma unroll
    for (int i = 0; i < 4; ++i) {
        int j = idx + i;
        if (j < M) rowptr[j] = run;
        run += v[i];
    }
}

// pass 2: single block exclusive-scans the block totals (NBLK <= 1024)
__global__ __launch_bounds__(1024) void scan_top_kernel(int* __restrict__ bsum, int NBLK) {
    __shared__ int ps[1024];
    const int tid = threadIdx.x;
    int v = (tid < NBLK) ? bsum[tid] : 0;
    ps[tid] = v;
    __syncthreads();
    for (int off = 1; off < 1024; off <<= 1) {
        int t = (tid >= off) ? ps[tid - off] : 0;
        __syncthreads();
        ps[tid] += t;
        __syncthreads();
    }
    int ex = (tid == 0) ? 0 : ps[tid - 1];
    if (tid < NBLK) bsum[tid] = ex;
}

// pass 3: add block offsets; write rowptr[M] = ET (known total)
__global__ __launch_bounds__(256) void scan_add_kernel(int* __restrict__ rowptr,
                                                       const int* __restrict__ bsum,
                                                       int M, int ET) {
    int idx = blockIdx.x * 256 + threadIdx.x;
    if (idx < M) rowptr[idx] += bsum[idx >> 10];
    if (idx == 0) rowptr[M] = ET;
}

// stores BYTE offsets (src * 4096): both gat layers use row stride 2048 bf16
__global__ __launch_bounds__(256) void scatter_kernel(const int* __restrict__ ei,
                                                      const int* __restrict__ rowptr,
                                                      int* __restrict__ cursor,
                                                      int* __restrict__ csr_off,
                                                      int E, int N, int NB) {
    int e = blockIdx.x * 256 + threadIdx.x;
    if (e >= E + N) return;
    int s, d;
    if (e < E) { s = ei[e]; d = ei[(size_t)E + e]; }
    else       { s = e - E; d = e - E; }
    size_t b = (size_t)d * NB + (s >> 10);
    int pos = atomicAdd(&cursor[b], 1);
    csr_off[rowptr[b] + pos] = s * 4096;
}

// ---------------------------------------------------------------- weight prep
// z=0..6: LDS-tiled transpose+cast; z=7: bias concat (fused, saves a dispatch)
__global__ __launch_bounds__(256) void transpose_w_kernel(
        const float* __restrict__ W_in,
        const float* __restrict__ c1_Wl, const float* __restrict__ c1_Wr,
        const float* __restrict__ a_Wl, const float* __restrict__ a_Wr,
        const float* __restrict__ k_Wl, const float* __restrict__ k_Wr,
        bf16* __restrict__ Wt,
        const float* __restrict__ c1_bl, const float* __restrict__ c1_br,
        const float* __restrict__ a_bl, const float* __restrict__ a_br,
        const float* __restrict__ k_bl, const float* __restrict__ k_br,
        float* __restrict__ b1, float* __restrict__ bak) {
    if (blockIdx.z == 7) {                       // bias slice
        int flat = blockIdx.y * 16 + blockIdx.x;
        if (flat >= 12) return;
        int i = flat * 256 + threadIdx.x;
        if (i < 1024) {
            b1[i] = (i < 512) ? c1_bl[i] : c1_br[i - 512];
        } else if (i < 3072) {
            int j = i - 1024;                    // [a_bl | a_br | k_bl | k_br]
            const float* b = (j < 512) ? a_bl : (j < 1024) ? a_br
                           : (j < 1536) ? k_bl : k_br;
            bak[j] = b[j & 511];
        }
        return;
    }
    __shared__ float tile[32][33];
    const float* src; int nc, drow;
    switch (blockIdx.z) {
        case 0: src = W_in;  nc = 128; drow = 0;    break;
        case 1: src = c1_Wl; nc = 512; drow = 128;  break;
        case 2: src = c1_Wr; nc = 512; drow = 640;  break;
        case 3: src = a_Wl;  nc = 512; drow = 1152; break;
        case 4: src = a_Wr;  nc = 512; drow = 1664; break;
        case 5: src = k_Wl;  nc = 512; drow = 2176; break;
        default: src = k_Wr; nc = 512; drow = 2688; break;
    }
    const int n0 = blockIdx.x * 32;
    if (n0 >= nc) return;
    const int k0 = blockIdx.y * 32;
    const int tx = threadIdx.x & 31, ty = threadIdx.x >> 5;
#pragma unroll
    for (int i = 0; i < 4; ++i)
        tile[ty + i * 8][tx] = src[(size_t)(k0 + ty + i * 8) * nc + n0 + tx];
    __syncthreads();
#pragma unroll
    for (int i = 0; i < 4; ++i)
        Wt[(size_t)(drow + n0 + ty + i * 8) * 128 + k0 + tx] =
            __float2bfloat16(tile[tx][ty + i * 8]);
}

// ---------------------------------------------------------------- MFMA GEMM
__global__ __launch_bounds__(256, 2) void gemm_mfma_kernel(
        const float* __restrict__ A, const bf16* __restrict__ Ab,
        const bf16* __restrict__ Wt,
        const float* __restrict__ bias,
        float* __restrict__ outF, bf16* __restrict__ outB,
        int M, int ldc, int relu) {
    __shared__ short As[128][136];   // [m][k]
    __shared__ short Bs[128][136];   // [n][k]
    const int tid = threadIdx.x;
    const int m0 = blockIdx.x * 128;
    const int n0 = blockIdx.y * 128;

    if (Ab) {
        short8 zero8;
#pragma unroll
        for (int q = 0; q < 8; ++q) zero8[q] = 0;
#pragma unroll
        for (int i = 0; i < 8; ++i) {            // stage A (bf16 direct)
            int idx = i * 256 + tid;
            int r = idx >> 4, k8 = (idx & 15) * 8;
            int gm = m0 + r;
            short8 s = (gm < M) ? *(const short8*)&Ab[(size_t)gm * 128 + k8] : zero8;
            *(short8*)&As[r][k8] = s;
        }
    } else {
#pragma unroll
        for (int i = 0; i < 16; ++i) {           // stage A (fp32 -> bf16)
            int idx = i * 256 + tid;
            int r = idx >> 5, k4 = (idx & 31) * 4;
            int gm = m0 + r;
            float4 v = (gm < M) ? *(const float4*)&A[(size_t)gm * 128 + k4]
                                : make_float4(0.f, 0.f, 0.f, 0.f);
            short4_t s;
            s.x = f2bs(v.x); s.y = f2bs(v.y); s.z = f2bs(v.z); s.w = f2bs(v.w);
            *(short4_t*)&As[r][k4] = s;
        }
    }
#pragma unroll
    for (int i = 0; i < 8; ++i) {                // stage B
        int idx = i * 256 + tid;
        int nr = idx >> 4, k8 = (idx & 15) * 8;
        *(short8*)&Bs[nr][k8] = *(const short8*)&Wt[(size_t)(n0 + nr) * 128 + k8];
    }
    __syncthreads();

    const int lane = tid & 63;
    const int w = tid >> 6;
    const int wm = (w >> 1) * 64, wn = (w & 1) * 64;
    const int fr = lane & 15;
    const int fq = (lane >> 4) * 8;

    float4_t acc[4][4] = {};
#pragma unroll
    for (int kk = 0; kk < 128; kk += 32) {
        short8 a[4], b[4];
#pragma unroll
        for (int t = 0; t < 4; ++t) a[t] = *(const short8*)&As[wm + t * 16 + fr][kk + fq];
#pragma unroll
        for (int t = 0; t < 4; ++t) b[t] = *(const short8*)&Bs[wn + t * 16 + fr][kk + fq];
#pragma unroll
        for (int ti = 0; ti < 4; ++ti)
#pragma unroll
            for (int tj = 0; tj < 4; ++tj)
                acc[ti][tj] = __builtin_amdgcn_mfma_f32_16x16x32_bf16(
                    a[ti], b[tj], acc[ti][tj], 0, 0, 0);
    }

    const int r0 = (lane >> 4) * 4;              // C/D: col=lane&15, row=quad*4+reg
#pragma unroll
    for (int ti = 0; ti < 4; ++ti) {
#pragma unroll
        for (int tj = 0; tj < 4; ++tj) {
            int col = n0 + wn + tj * 16 + fr;
            float bz = bias[col];
#pragma unroll
            for (int r = 0; r < 4; ++r) {
                size_t row = m0 + wm + ti * 16 + r0 + r;
                float v = acc[ti][tj][r] + bz;
                if (relu) v = fmaxf(v, 0.f);
                if (outF) outF[row * ldc + col] = v;
                if (outB) outB[row * ldc + col] = __float2bfloat16(v);
            }
        }
    }
}

// ---------------------------------------------------------------- GAT layer 1
// ONE WAVE PER NODE (4 nodes/block, no barriers, no LDS). 4 heads x 16 lanes,
// 8 ch/lane. e wave-uniform -> scalar loop guards. Depth-2 row prefetch.
__global__ __launch_bounds__(256) void gat_kernel(
        const bf16* __restrict__ xl, const bf16* __restrict__ xr,  // stride 2048
        const float* __restrict__ att,      // [4*128]
        const int* __restrict__ rowptr, const int* __restrict__ csr_off,
        const float* __restrict__ h_res,    // [N,128]
        const float* __restrict__ gbias,    // [128]
        const float* __restrict__ ln_g, const float* __restrict__ ln_b,
        float* __restrict__ h_out, bf16* __restrict__ h_outb, int N, int NB) {
    const int n = blockIdx.x * 4 + (threadIdx.x >> 6);
    if (n >= N) return;
    const int lane = threadIdx.x & 63;
    const int sl = lane & 15;
    const int hc = (lane >> 4) * 128 + sl * 8;   // channel in [0,512)

    float2v a2[4], xr2[4];
    {
        const float* ap = att + hc;
        short8 v = *(const short8*)(xr + (size_t)n * 2048 + hc);
        const unsigned int* uv = (const unsigned int*)&v;
#pragma unroll
        for (int j = 0; j < 4; ++j) {
            a2[j].x = ap[2 * j]; a2[j].y = ap[2 * j + 1];
            unsigned u = uv[j];
            xr2[j].x = __uint_as_float(u << 16);
            xr2[j].y = __uint_as_float(u & 0xffff0000u);
        }
    }
    const int rs = rowptr[(size_t)n * NB];
    const int re = rowptr[(size_t)n * NB + NB];
    const char* xlh = (const char*)xl + (size_t)hc * 2;

    float l = 0.f;
    float2v acc2[4] = {};
    int o0 = csr_off[rs];
    short8 va = *(const short8*)(xlh + o0);
    int o1 = (rs + 1 < re) ? csr_off[rs + 1] : o0;
    short8 vb = *(const short8*)(xlh + o1);
    int o2 = (rs + 2 < re) ? csr_off[rs + 2] : o0;

    for (int e = rs; e < re; ++e) {
        short8 cur = va; va = vb;
        if (e + 2 < re) {                        // wave-uniform -> scalar branch
            vb = *(const short8*)(xlh + o2);
            o2 = (e + 3 < re) ? csr_off[e + 3] : o0;
        }
        const unsigned int* uv = (const unsigned int*)&cur;
        float2v pa = {0.f, 0.f}, pb = {0.f, 0.f};
        float2v xs[4];
#pragma unroll
        for (int j = 0; j < 4; ++j) {
            unsigned u = uv[j];
            float2v x;
            x.x = __uint_as_float(u << 16);
            x.y = __uint_as_float(u & 0xffff0000u);
            xs[j] = x;
            float2v t = x + xr2[j];
            float2v ta = __builtin_bit_cast(float2v,
                           __builtin_bit_cast(uint2v, t) & 0x7fffffffu);
            pa = __builtin_elementwise_fma(a2[j], t, pa);
            pb = __builtin_elementwise_fma(a2[j], ta, pb);
        }
        float p = rowsum16(0.6f * (pa.x + pa.y) + 0.4f * (pb.x + pb.y));
        float wv = __expf(fminf(p, 60.f));       // scores O(+-4); clamp for safety
        l += wv;
        float2v ws = {wv, wv};
#pragma unroll
        for (int j = 0; j < 4; ++j)
            acc2[j] = __builtin_elementwise_fma(ws, xs[j], acc2[j]);
    }

    float* accf = (float*)acc2;
    const float inv = 0.25f / (l + 1e-16f);
#pragma unroll
    for (int j = 0; j < 8; ++j) accf[j] *= inv;
#pragma unroll
    for (int off = 16; off <= 32; off <<= 1)
#pragma unroll
        for (int j = 0; j < 8; ++j) accf[j] += __shfl_xor(accf[j], off, 64);

    if (lane < 16) {
        const int cb = sl * 8;
        const float* hr = h_res + (size_t)n * 128 + cb;
        float vv[8];
#pragma unroll
        for (int j = 0; j < 8; ++j) vv[j] = accf[j] + gbias[cb + j] + hr[j];
        float t1 = 0.f, t2 = 0.f;
#pragma unroll
        for (int j = 0; j < 8; ++j) { t1 += vv[j]; t2 += vv[j] * vv[j]; }
        const float s1 = rowsum16(t1), s2 = rowsum16(t2);
        const float mu   = s1 * 0.0078125f;
        const float var  = s2 * 0.0078125f - mu * mu;
        const float rstd = rsqrtf(var + 1e-5f);
        float y[8];
#pragma unroll
        for (int j = 0; j < 8; ++j) {
            y[j] = fmaf((vv[j] - mu) * rstd, ln_g[cb + j], ln_b[cb + j]);
            y[j] = fmaxf(y[j], 0.f);
        }
        *(float4*)(h_out + (size_t)n * 128 + cb) = make_float4(y[0], y[1], y[2], y[3]);
        *(float4*)(h_out + (size_t)n * 128 + cb + 4) = make_float4(y[4], y[5], y[6], y[7]);
        short8 yb;
#pragma unroll
        for (int j = 0; j < 8; ++j) yb[j] = f2bs(y[j]);
        *(short8*)(h_outb + (size_t)n * 128 + cb) = yb;
    }
}

// ---------------------------------------------------------------- merged actor+critic GAT
// cat cols [xla|xra|xlk|xrk]: per edge read xla at +0 and xlk at +2048B of the
// same 4KB row (R4-proven split). Lanes 0-15 epilogue actor, 16-31 critic.
__global__ __launch_bounds__(256) void gat2_kernel(
        const bf16* __restrict__ cat,       // [*][2048]
        const float* __restrict__ a_att, const float* __restrict__ k_att,
        const int* __restrict__ rowptr, const int* __restrict__ csr_off,
        const float* __restrict__ h_res,    // [N,128] = h1
        const float* __restrict__ a_gb, const float* __restrict__ k_gb,
        const float* __restrict__ aln_g, const float* __restrict__ aln_b,
        const float* __restrict__ kln_g, const float* __restrict__ kln_b,
        const float* __restrict__ ah_W, const float* __restrict__ ah_b,
        const float* __restrict__ kh_W, const float* __restrict__ kh_b,
        float* __restrict__ out_logits, float* __restrict__ out_value,
        int N, int NB) {
    const int n = blockIdx.x * 4 + (threadIdx.x >> 6);
    if (n >= N) return;
    const int lane = threadIdx.x & 63;
    const int sl = lane & 15;
    const int hc = (lane >> 4) * 128 + sl * 8;

    float2v aa[4], ak[4], xra[4], xrk[4];
    {
        const float* apa = a_att + hc;
        const float* apk = k_att + hc;
        short8 vra = *(const short8*)(cat + (size_t)n * 2048 + 512 + hc);
        short8 vrk = *(const short8*)(cat + (size_t)n * 2048 + 1536 + hc);
        const unsigned int* ua = (const unsigned int*)&vra;
        const unsigned int* uk = (const unsigned int*)&vrk;
#pragma unroll
        for (int j = 0; j < 4; ++j) {
            aa[j].x = apa[2 * j]; aa[j].y = apa[2 * j + 1];
            ak[j].x = apk[2 * j]; ak[j].y = apk[2 * j + 1];
            unsigned u = ua[j];
            xra[j].x = __uint_as_float(u << 16);
            xra[j].y = __uint_as_float(u & 0xffff0000u);
            u = uk[j];
            xrk[j].x = __uint_as_float(u << 16);
            xrk[j].y = __uint_as_float(u & 0xffff0000u);
        }
    }
    const int rs = rowptr[(size_t)n * NB];
    const int re = rowptr[(size_t)n * NB + NB];
    const char* xlh = (const char*)cat + (size_t)hc * 2;   // +o: xla, +o+2048: xlk

    float la = 0.f, lk = 0.f;
    float2v acca[4] = {}, acck[4] = {};
    int o0 = csr_off[rs];
    short8 vaa = *(const short8*)(xlh + o0);
    short8 vak = *(const short8*)(xlh + o0 + 2048);
    int o1 = (rs + 1 < re) ? csr_off[rs + 1] : o0;
    short8 vba = *(const short8*)(xlh + o1);
    short8 vbk = *(const short8*)(xlh + o1 + 2048);
    int o2 = (rs + 2 < re) ? csr_off[rs + 2] : o0;

    for (int e = rs; e < re; ++e) {
        short8 ca = vaa, ck = vak;
        vaa = vba; vak = vbk;
        if (e + 2 < re) {
            vba = *(const short8*)(xlh + o2);
            vbk = *(const short8*)(xlh + o2 + 2048);
            o2 = (e + 3 < re) ? csr_off[e + 3] : o0;
        }
        const unsigned int* ua = (const unsigned int*)&ca;
        const unsigned int* uk = (const unsigned int*)&ck;
        float2v paa = {0.f, 0.f}, pba = {0.f, 0.f};
        float2v pak = {0.f, 0.f}, pbk = {0.f, 0.f};
        float2v xsa[4], xsk[4];
#pragma unroll
        for (int j = 0; j < 4; ++j) {
            unsigned u = ua[j];
            float2v x;
            x.x = __uint_as_float(u << 16);
            x.y = __uint_as_float(u & 0xffff0000u);
            xsa[j] = x;
            float2v t = x + xra[j];
            float2v ta = __builtin_bit_cast(float2v,
                           __builtin_bit_cast(uint2v, t) & 0x7fffffffu);
            paa = __builtin_elementwise_fma(aa[j], t, paa);
            pba = __builtin_elementwise_fma(aa[j], ta, pba);

            u = uk[j];
            x.x = __uint_as_float(u << 16);
            x.y = __uint_as_float(u & 0xffff0000u);
            xsk[j] = x;
            t = x + xrk[j];
            ta = __builtin_bit_cast(float2v,
                   __builtin_bit_cast(uint2v, t) & 0x7fffffffu);
            pak = __builtin_elementwise_fma(ak[j], t, pak);
            pbk = __builtin_elementwise_fma(ak[j], ta, pbk);
        }
        float p_a = rowsum16(0.6f * (paa.x + paa.y) + 0.4f * (pba.x + pba.y));
        float p_k = rowsum16(0.6f * (pak.x + pak.y) + 0.4f * (pbk.x + pbk.y));
        float wa = __expf(fminf(p_a, 60.f));
        float wk = __expf(fminf(p_k, 60.f));
        la += wa; lk += wk;
        float2v wsa = {wa, wa}, wsk = {wk, wk};
#pragma unroll
        for (int j = 0; j < 4; ++j) {
            acca[j] = __builtin_elementwise_fma(wsa, xsa[j], acca[j]);
            acck[j] = __builtin_elementwise_fma(wsk, xsk[j], acck[j]);
        }
    }

    float* afa = (float*)acca;
    float* afk = (float*)acck;
    const float inva = 0.25f / (la + 1e-16f);
    const float invk = 0.25f / (lk + 1e-16f);
#pragma unroll
    for (int j = 0; j < 8; ++j) { afa[j] *= inva; afk[j] *= invk; }
#pragma unroll
    for (int off = 16; off <= 32; off <<= 1)
#pragma unroll
        for (int j = 0; j < 8; ++j) {
            afa[j] += __shfl_xor(afa[j], off, 64);
            afk[j] += __shfl_xor(afk[j], off, 64);
        }

    if (lane < 32) {
        const int cb = sl * 8;
        const float* hr = h_res + (size_t)n * 128 + cb;
        float hrv[8];
#pragma unroll
        for (int j = 0; j < 8; ++j) hrv[j] = hr[j];
        if (lane < 16) {                         // actor
            float vv[8];
#pragma unroll
            for (int j = 0; j < 8; ++j) vv[j] = afa[j] + a_gb[cb + j] + hrv[j];
            float t1 = 0.f, t2 = 0.f;
#pragma unroll
            for (int j = 0; j < 8; ++j) { t1 += vv[j]; t2 += vv[j] * vv[j]; }
            const float s1 = rowsum16(t1), s2 = rowsum16(t2);
            const float mu   = s1 * 0.0078125f;
            const float var  = s2 * 0.0078125f - mu * mu;
            const float rstd = rsqrtf(var + 1e-5f);
            float d = 0.f;
#pragma unroll
            for (int j = 0; j < 8; ++j) {
                float y = fmaf((vv[j] - mu) * rstd, aln_g[cb + j], aln_b[cb + j]);
                d += fmaxf(y, 0.f) * ah_W[cb + j];
            }
            d = rowsum16(d);
            if (sl == 0) out_logits[n] = d + ah_b[0];
        } else {                                 // critic
            float vv[8];
#pragma unroll
            for (int j = 0; j < 8; ++j) vv[j] = afk[j] + k_gb[cb + j] + hrv[j];
            float t1 = 0.f, t2 = 0.f;
#pragma unroll
            for (int j = 0; j < 8; ++j) { t1 += vv[j]; t2 += vv[j] * vv[j]; }
            const float s1 = rowsum16(t1), s2 = rowsum16(t2);
            const float mu   = s1 * 0.0078125f;
            const float var  = s2 * 0.0078125f - mu * mu;
            const float rstd = rsqrtf(var + 1e-5f);
            float d = 0.f;
#pragma unroll
            for (int j = 0; j < 8; ++j) {
                float y = fmaf((vv[j] - mu) * rstd, kln_g[cb + j], kln_b[cb + j]);
                d += fmaxf(y, 0.f) * kh_W[cb + j];
            }
            d = rowsum16(d);
            if (sl == 0) out_value[n] = d + kh_b[0];
        }
    }
}

// ---------------------------------------------------------------- launch
extern "C" void kernel_launch(void* const* d_in, const int* in_sizes, int n_in,
                              void* d_out, int out_size, void* d_ws, size_t ws_size,
                              hipStream_t stream) {
    const float* x      = (const float*)d_in[0];
    const int*   ei     = (const int*)  d_in[1];
    const float* W_in   = (const float*)d_in[2];
    const float* b_in   = (const float*)d_in[3];
    const float* c1_Wl  = (const float*)d_in[4];
    const float* c1_bl  = (const float*)d_in[5];
    const float* c1_Wr  = (const float*)d_in[6];
    const float* c1_br  = (const float*)d_in[7];
    const float* c1_att = (const float*)d_in[8];
    const float* c1_b   = (const float*)d_in[9];
    const float* ln1_g  = (const float*)d_in[10];
    const float* ln1_b  = (const float*)d_in[11];
    const float* a_Wl   = (const float*)d_in[12];
    const float* a_bl   = (const float*)d_in[13];
    const float* a_Wr   = (const float*)d_in[14];
    const float* a_br   = (const float*)d_in[15];
    const float* a_att  = (const float*)d_in[16];
    const float* a_b    = (const float*)d_in[17];
    const float* aln_g  = (const float*)d_in[18];
    const float* aln_b  = (const float*)d_in[19];
    const float* ah_W   = (const float*)d_in[20];
    const float* ah_b   = (const float*)d_in[21];
    const float* k_Wl   = (const float*)d_in[22];
    const float* k_bl   = (const float*)d_in[23];
    const float* k_Wr   = (const float*)d_in[24];
    const float* k_br   = (const float*)d_in[25];
    const float* k_att  = (const float*)d_in[26];
    const float* k_b    = (const float*)d_in[27];
    const float* kln_g  = (const float*)d_in[28];
    const float* kln_b  = (const float*)d_in[29];
    const float* kh_W   = (const float*)d_in[30];
    const float* kh_b   = (const float*)d_in[31];

    const int N  = in_sizes[0] / 128;       // 20000
    const int E  = in_sizes[1] / 2;         // 320000
    const int ET = E + N;
    const int MB = (N + 127) / 128;         // 157
    const int Npad = MB * 128;              // 20096
    const int NB = (N + 1023) >> 10;        // src buckets (20): 4MB of rows each
    const int M  = N * NB;                  // bucketed CSR cells
    const int NBLK = (M + 1023) / 1024;     // scan blocks (391)

    char* ws = (char*)d_ws;
    size_t off = 0;
    auto alloc = [&](size_t bytes) -> void* {
        void* p = ws + off;
        off += (bytes + 255) & ~(size_t)255;
        return p;
    };
    int*   rowptr  = (int*)alloc((size_t)(M + 1) * 4);
    int*   cntcur  = (int*)alloc((size_t)2 * M * 4);   // cnt | cursor
    int*   bsum    = (int*)alloc((size_t)NBLK * 4);
    int*   csr_off = (int*)alloc((size_t)ET * 4);
    float* h0      = (float*)alloc((size_t)Npad * 128 * 4);
    bf16*  h0b     = (bf16*)alloc((size_t)Npad * 128 * 2);
    float* h1      = (float*)alloc((size_t)Npad * 128 * 4);
    bf16*  h1b     = (bf16*)alloc((size_t)Npad * 128 * 2);
    bf16*  Wt      = (bf16*)alloc((size_t)3200 * 128 * 2);
    float* b1cat   = (float*)alloc(1024 * 4);
    float* bakcat  = (float*)alloc(2048 * 4);
    bf16*  cat     = (bf16*)alloc((size_t)Npad * 2048 * 2);  // row stride 2048 always

    int* cnt    = cntcur;
    int* cursor = cntcur + M;
    const bf16* Wt_in = Wt;
    const bf16* Wt_1  = Wt + 128 * 128;
    const bf16* Wt_ak = Wt + 128 * 128 + 1024 * 128;

    float* out_logits = (float*)d_out;
    float* out_value  = (float*)d_out + N;

    // CSR (bucketed; shared by all GAT layers) + weight prep
    hipMemsetAsync(cntcur, 0, (size_t)2 * M * 4, stream);
    count_kernel<<<(ET + 255) / 256, 256, 0, stream>>>(ei, cnt, E, N, NB);
    transpose_w_kernel<<<dim3(16, 4, 8), 256, 0, stream>>>(
        W_in, c1_Wl, c1_Wr, a_Wl, a_Wr, k_Wl, k_Wr, Wt,
        c1_bl, c1_br, a_bl, a_br, k_bl, k_br, b1cat, bakcat);
    scan_blk_kernel<<<NBLK, 256, 0, stream>>>(cnt, rowptr, bsum, M);
    scan_top_kernel<<<1, 1024, 0, stream>>>(bsum, NBLK);
    scan_add_kernel<<<(M + 255) / 256, 256, 0, stream>>>(rowptr, bsum, M, ET);
    scatter_kernel<<<(ET + 255) / 256, 256, 0, stream>>>(ei, rowptr, cursor, csr_off,
                                                         E, N, NB);

    // h0 = relu(x @ W_in + b_in)  (fp32 for residual + bf16 for next GEMM's A)
    gemm_mfma_kernel<<<dim3(MB, 1), 256, 0, stream>>>(x, nullptr, Wt_in, b_in,
                                                      h0, h0b, N, 128, 1);
    // layer-1: [xl1|xr1] = h0 @ [Wl|Wr]  (bf16 A, cols 0..1023, row stride 2048)
    gemm_mfma_kernel<<<dim3(MB, 8), 256, 0, stream>>>(nullptr, h0b, Wt_1, b1cat,
                                                      nullptr, cat, Npad, 2048, 0);
    gat_kernel<<<(N + 3) / 4, 256, 0, stream>>>(cat, cat + 512, c1_att, rowptr, csr_off,
                                      h0, c1_b, ln1_g, ln1_b, h1, h1b, N, NB);
    // actor+critic: [xla|xra|xlk|xrk] = h1 @ [aWl|aWr|kWl|kWr]
    gemm_mfma_kernel<<<dim3(MB, 16), 256, 0, stream>>>(nullptr, h1b, Wt_ak, bakcat,
                                                       nullptr, cat, Npad, 2048, 0);
    gat2_kernel<<<(N + 3) / 4, 256, 0, stream>>>(cat, a_att, k_att, rowptr, csr_off,
                                      h1, a_b, k_b, aln_g, aln_b, kln_g, kln_b,
                                      ah_W, ah_b, kh_W, kh_b,
                                      out_logits, out_value, N, NB);
}